// Round 8
// baseline (1126.129 us; speedup 1.0000x reference)
//
#include <hip/hip_runtime.h>
#include <hip/hip_bf16.h>
#include <cstdint>

typedef float f4  __attribute__((ext_vector_type(4)));
typedef short s8v __attribute__((ext_vector_type(8)));   // 8 bf16 (4 VGPRs)
typedef short s4v __attribute__((ext_vector_type(4)));   // 4 bf16 (2 VGPRs)
typedef int   i4v __attribute__((ext_vector_type(4)));

#define BHTD 3145728    // B*H*T*D = 2*12*2048*64
#define BTC  3145728
#define NT   2048
#define NC   768
#define NEG  -1e30f
// fixed-shift softmax: p = exp(s - 20) = 2^(s*log2e - 20*log2e)
#define EXC1 1.4426950408889634f
#define EXC0 -28.853900817779268f

static __device__ __forceinline__ short bfbits(float f) {
    return __builtin_bit_cast(short, __float2bfloat16(f));
}
static __device__ __forceinline__ float bf2f(short s) {
    return __builtin_bit_cast(float, (int)(((unsigned int)(unsigned short)s) << 16));
}
static __device__ __forceinline__ float fast_exp2(float x) {
    return __builtin_amdgcn_exp2f(x);    // v_exp_f32
}

// ---------------------------------------------------------------------------
// Kernel 1: MFMA QKV projection (unchanged).
// Outputs bf16: Q (pre-scaled 1/8), K in [var][part][B,H,T,D]; V in [B,H,D,T].
// ---------------------------------------------------------------------------
__global__ __launch_bounds__(256) void qkv_proj_mfma(
    const float* __restrict__ x, const float* __restrict__ xl,
    const float* __restrict__ xu, const float* __restrict__ W,
    short* __restrict__ qkvb)
{
    __shared__ short sm[4 * 64 * 40];
    short* Ax = sm;
    short* Am = sm + 2560;
    short* Ar = sm + 5120;
    short* Bw = sm + 7680;
    short* Eb = sm;                     // epilogue [64][72]

    const int j0 = blockIdx.x * 64;
    const int n0 = blockIdx.y * 64;
    const int t  = threadIdx.x;
    const int wv = t >> 6, lane = t & 63, quad = lane >> 4, l16 = lane & 15;
    const int rw = t >> 2, koff = (t & 3) * 8;

    f4 aN[4], aM[4], aR[4];
#pragma unroll
    for (int i = 0; i < 4; i++) { aN[i] = f4{0,0,0,0}; aM[i] = f4{0,0,0,0}; aR[i] = f4{0,0,0,0}; }

    for (int k0 = 0; k0 < NC; k0 += 32) {
        const size_t xo = (size_t)(n0 + rw) * NC + k0 + koff;
        const f4 x0 = *(const f4*)&x[xo],  x1 = *(const f4*)&x[xo + 4];
        const f4 l0 = *(const f4*)&xl[xo], l1 = *(const f4*)&xl[xo + 4];
        const f4 u0 = *(const f4*)&xu[xo], u1 = *(const f4*)&xu[xo + 4];
        const size_t wo = (size_t)(j0 + rw) * NC + k0 + koff;
        const f4 w0 = *(const f4*)&W[wo], w1 = *(const f4*)&W[wo + 4];
        s8v vx, vm, vr, vw;
#pragma unroll
        for (int i = 0; i < 4; i++) {
            vx[i]     = bfbits(x0[i]);              vx[4 + i] = bfbits(x1[i]);
            vm[i]     = bfbits(0.5f * (l0[i] + u0[i])); vm[4 + i] = bfbits(0.5f * (l1[i] + u1[i]));
            vr[i]     = bfbits(0.5f * (u0[i] - l0[i])); vr[4 + i] = bfbits(0.5f * (u1[i] - l1[i]));
            vw[i]     = bfbits(w0[i]);              vw[4 + i] = bfbits(w1[i]);
        }
        __syncthreads();
        *(s8v*)&Ax[rw * 40 + koff] = vx;
        *(s8v*)&Am[rw * 40 + koff] = vm;
        *(s8v*)&Ar[rw * 40 + koff] = vr;
        *(s8v*)&Bw[rw * 40 + koff] = vw;
        __syncthreads();
        const s8v fx = *(const s8v*)&Ax[(wv * 16 + l16) * 40 + quad * 8];
        const s8v fm = *(const s8v*)&Am[(wv * 16 + l16) * 40 + quad * 8];
        const s8v fr = *(const s8v*)&Ar[(wv * 16 + l16) * 40 + quad * 8];
#pragma unroll
        for (int nt = 0; nt < 4; ++nt) {
            const s8v fb = *(const s8v*)&Bw[(nt * 16 + l16) * 40 + quad * 8];
            i4v bi = __builtin_bit_cast(i4v, fb);
#pragma unroll
            for (int i = 0; i < 4; i++) bi[i] &= 0x7fff7fff;
            const s8v fa = __builtin_bit_cast(s8v, bi);
            aN[nt] = __builtin_amdgcn_mfma_f32_16x16x32_bf16(fx, fb, aN[nt], 0, 0, 0);
            aM[nt] = __builtin_amdgcn_mfma_f32_16x16x32_bf16(fm, fb, aM[nt], 0, 0, 0);
            aR[nt] = __builtin_amdgcn_mfma_f32_16x16x32_bf16(fr, fa, aR[nt], 0, 0, 0);
        }
    }

    const int p = j0 / NC, hh = (j0 % NC) >> 6;
    const float qsc = (p == 0) ? 0.125f : 1.0f;
    const int cc16 = (t & 3) * 16;
    for (int var = 0; var < 3; ++var) {
        __syncthreads();
#pragma unroll
        for (int nt = 0; nt < 4; ++nt)
#pragma unroll
            for (int r = 0; r < 4; ++r) {
                const float v = ((var == 0) ? aN[nt][r]
                              : (var == 1) ? aM[nt][r] - aR[nt][r]
                                           : aM[nt][r] + aR[nt][r]) * qsc;
                Eb[(wv * 16 + quad * 4 + r) * 72 + nt * 16 + l16] = bfbits(v);
            }
        __syncthreads();
        short* dst = qkvb + (size_t)(var * 3 + p) * BHTD;
        if (p < 2) {
            const int token = n0 + rw, b = token >> 11, tt = token & 2047;
            const size_t o = ((size_t)(b * 12 + hh) * NT + tt) * 64 + cc16;
            *(s8v*)&dst[o]     = *(const s8v*)&Eb[rw * 72 + cc16];
            *(s8v*)&dst[o + 8] = *(const s8v*)&Eb[rw * 72 + cc16 + 8];
        } else {
            const int d = rw;
            s8v e0, e1;
#pragma unroll
            for (int i = 0; i < 8; i++) e0[i] = Eb[(cc16 + i) * 72 + d];
#pragma unroll
            for (int i = 0; i < 8; i++) e1[i] = Eb[(cc16 + 8 + i) * 72 + d];
            const int token0 = n0 + cc16, b = token0 >> 11, tt = token0 & 2047;
            const size_t o = ((size_t)(b * 12 + hh) * 64 + d) * NT + tt;
            *(s8v*)&dst[o]     = e0;
            *(s8v*)&dst[o + 8] = e1;
        }
    }
}

// ---------------------------------------------------------------------------
// Kernel 2: register-resident flash, ONE (qk-corner, v-variant) per block.
// z=0: nominal -> ybuf fp32. z=1..8: combo c=z-1 (qk corner c>>1, v c&1)
// -> cand[c] normalized bf16 (out_proj min/maxes the 8 combos).
// S^T = K·Q^T keeps P in registers (zero LDS, zero barriers).
// K and V both prefetched one k-tile ahead. Balanced qt pairing per block.
// ---------------------------------------------------------------------------
__global__ __launch_bounds__(256, 3) void flash_mfma_all(
    const short* __restrict__ qkvb, float* __restrict__ ybuf,
    short* __restrict__ cand)
{
    const int bx = blockIdx.x;             // 0..7
    const int bh = blockIdx.y;
    const int z  = blockIdx.z;             // 0..8
    const int t  = threadIdx.x;
    const int wv = t >> 6, lane = t & 63, quad = lane >> 4, l16 = lane & 15;

    const bool nom = (z == 0);
    const int c   = z - 1;                 // combo 0..7 (when !nom)
    const int qvi = nom ? 0 : 1 + (c >> 2);
    const int kvi = nom ? 0 : 1 + ((c >> 1) & 1);
    const int vi  = nom ? 0 : 1 + (c & 1);

    const size_t hb = (size_t)bh * (NT * 64);
    const short* Qp  = qkvb + (size_t)(qvi * 3 + 0) * BHTD + hb;  // [t][d]
    const short* Kp0 = qkvb + (size_t)(kvi * 3 + 1) * BHTD + hb;  // [t][d]
    const short* Vp  = qkvb + (size_t)(vi  * 3 + 2) * BHTD + hb;  // [d][t]

    const int koffl = l16 * 64 + quad * 8;     // K A-frag lane offset
    const int voffl = l16 * NT + quad * 4;     // V B-frag lane offset

    for (int ph = 0; ph < 2; ++ph) {
        const int qt  = ph ? bx : 15 - bx;
        const int q0w = qt * 128 + 32 * wv;    // this wave's 32 q-rows

        s8v qf[2][2];
#pragma unroll
        for (int qh = 0; qh < 2; ++qh)
#pragma unroll
            for (int ch = 0; ch < 2; ++ch)
                qf[qh][ch] = *(const s8v*)&Qp[(size_t)(q0w + qh * 16 + l16) * 64 + ch * 32 + quad * 8];

        float lsum[2] = {0.f, 0.f};
        f4 acc[2][4];
#pragma unroll
        for (int qh = 0; qh < 2; ++qh)
#pragma unroll
            for (int dt = 0; dt < 4; ++dt) acc[qh][dt] = f4{0,0,0,0};

        const int myktn = 4 * qt + wv + 1;

        // prologue: K tile 0 + V tile 0
        const short* Kit = Kp0;
        s8v kfc[2][2];
        kfc[0][0] = *(const s8v*)&Kit[koffl];
        kfc[0][1] = *(const s8v*)&Kit[koffl + 32];
        kfc[1][0] = *(const s8v*)&Kit[koffl + 1024];
        kfc[1][1] = *(const s8v*)&Kit[koffl + 1056];
        s4v vfc[2][4];
#pragma unroll
        for (int kt2 = 0; kt2 < 2; ++kt2)
#pragma unroll
            for (int dt = 0; dt < 4; ++dt)
                vfc[kt2][dt] = *(const s4v*)&Vp[voffl + dt * 16 * NT + kt2 * 16];

        for (int kt = 0; kt < myktn; ++kt) {
            const int k0 = kt * 32;

            // ---- prefetch NEXT V tile (consumed next iter; deep window) ----
            s4v vfn[2][4];
#pragma unroll
            for (int kt2 = 0; kt2 < 2; ++kt2)
#pragma unroll
                for (int dt = 0; dt < 4; ++dt)
                    vfn[kt2][dt] = *(const s4v*)&Vp[voffl + dt * 16 * NT + k0 + 32 + kt2 * 16];

            // ---- S^T = K·Q^T ----
            f4 st[2][2];
#pragma unroll
            for (int kt2 = 0; kt2 < 2; ++kt2) { st[kt2][0] = f4{0,0,0,0}; st[kt2][1] = f4{0,0,0,0}; }
#pragma unroll
            for (int kt2 = 0; kt2 < 2; ++kt2)
#pragma unroll
                for (int ch = 0; ch < 2; ++ch) {
                    st[kt2][0] = __builtin_amdgcn_mfma_f32_16x16x32_bf16(kfc[kt2][ch], qf[0][ch], st[kt2][0], 0, 0, 0);
                    st[kt2][1] = __builtin_amdgcn_mfma_f32_16x16x32_bf16(kfc[kt2][ch], qf[1][ch], st[kt2][1], 0, 0, 0);
                }

            // ---- prefetch NEXT K tile (kfc consumed above) ----
            Kit += 32 * 64;
            kfc[0][0] = *(const s8v*)&Kit[koffl];
            kfc[0][1] = *(const s8v*)&Kit[koffl + 32];
            kfc[1][0] = *(const s8v*)&Kit[koffl + 1024];
            kfc[1][1] = *(const s8v*)&Kit[koffl + 1056];

            // ---- fixed-shift exp, mask, pack into PV A-frags ----
            s4v pa[2][2];
#pragma unroll
            for (int kt2 = 0; kt2 < 2; ++kt2)
#pragma unroll
                for (int qh = 0; qh < 2; ++qh) {
                    const int rowb = q0w + qh * 16;
                    const bool msk = (k0 + kt2 * 16 + 15 > rowb);
#pragma unroll
                    for (int r = 0; r < 4; ++r) {
                        float v = st[kt2][qh][r];
                        if (msk && (k0 + kt2 * 16 + quad * 4 + r > rowb + l16)) v = NEG;
                        const float p = fast_exp2(fmaf(v, EXC1, EXC0));
                        lsum[qh] += p;
                        pa[kt2][qh][r] = bfbits(p);
                    }
                }

            // ---- O += P·V (P in registers) ----
#pragma unroll
            for (int kt2 = 0; kt2 < 2; ++kt2)
#pragma unroll
                for (int qh = 0; qh < 2; ++qh)
#pragma unroll
                    for (int dt = 0; dt < 4; ++dt)
                        acc[qh][dt] = __builtin_amdgcn_mfma_f32_16x16x16bf16_1k(
                            pa[kt2][qh], vfc[kt2][dt], acc[qh][dt], 0, 0, 0);

            // rotate V
#pragma unroll
            for (int kt2 = 0; kt2 < 2; ++kt2)
#pragma unroll
                for (int dt = 0; dt < 4; ++dt) vfc[kt2][dt] = vfn[kt2][dt];
        } // kt

        // ---- deferred l reduction + cross-lane inv broadcast ----
        float invq[2];
#pragma unroll
        for (int qh = 0; qh < 2; ++qh) {
            float s = lsum[qh];
            s += __shfl_xor(s, 16, 64);
            s += __shfl_xor(s, 32, 64);
            invq[qh] = 1.f / s;
        }

#pragma unroll
        for (int qh = 0; qh < 2; ++qh)
#pragma unroll
            for (int r = 0; r < 4; ++r) {
                const float inv = __shfl(invq[qh], quad * 4 + r, 64);
                const size_t o = hb + (size_t)(q0w + qh * 16 + quad * 4 + r) * 64 + l16;
#pragma unroll
                for (int dt = 0; dt < 4; ++dt) {
                    if (nom) ybuf[o + dt * 16] = acc[qh][dt][r] * inv;
                    else     cand[(size_t)c * BHTD + o + dt * 16] = bfbits(acc[qh][dt][r] * inv);
                }
            }
    } // ph
}

// ---------------------------------------------------------------------------
// Kernel 3: MFMA output projection. z=0: A=y fp32; z=1: A=min of 8 combos;
// z=2: A=max of 8 combos. B=Wp (bf16). out fp32 via LDS re-layout.
// ---------------------------------------------------------------------------
__global__ __launch_bounds__(256) void out_proj_mfma(
    const float* __restrict__ ybuf, const short* __restrict__ cand,
    const float* __restrict__ Wp, float* __restrict__ out)
{
    __shared__ float smf[64 * 68];
    short* As = (short*)smf;
    short* Bs = As + 2560;
    float* Eb = smf;

    const int o  = blockIdx.z;
    const int j0 = blockIdx.x * 64, n0 = blockIdx.y * 64;
    const int t  = threadIdx.x;
    const int wv = t >> 6, lane = t & 63, quad = lane >> 4, l16 = lane & 15;
    const int rw = t >> 2, koff = (t & 3) * 8;

    f4 acc[4];
#pragma unroll
    for (int i = 0; i < 4; i++) acc[i] = f4{0,0,0,0};

    const int token = n0 + rw, b = token >> 11, tt = token & 2047;

    for (int k0 = 0; k0 < NC; k0 += 32) {
        const int hh = k0 >> 6, d0 = (k0 & 63) + koff;
        const size_t aoff = ((size_t)(b * 12 + hh) * NT + tt) * 64 + d0;
        s8v av;
        if (o == 0) {
            const f4 y0 = *(const f4*)&ybuf[aoff];
            const f4 y1 = *(const f4*)&ybuf[aoff + 4];
#pragma unroll
            for (int i = 0; i < 4; i++) { av[i] = bfbits(y0[i]); av[4 + i] = bfbits(y1[i]); }
        } else {
            float v[8];
            {
                const s8v c0 = *(const s8v*)&cand[aoff];
#pragma unroll
                for (int i = 0; i < 8; i++) v[i] = bf2f(c0[i]);
            }
#pragma unroll
            for (int q = 1; q < 8; ++q) {
                const s8v cq = *(const s8v*)&cand[(size_t)q * BHTD + aoff];
                if (o == 1) {
#pragma unroll
                    for (int i = 0; i < 8; i++) v[i] = fminf(v[i], bf2f(cq[i]));
                } else {
#pragma unroll
                    for (int i = 0; i < 8; i++) v[i] = fmaxf(v[i], bf2f(cq[i]));
                }
            }
#pragma unroll
            for (int i = 0; i < 8; i++) av[i] = bfbits(v[i]);
        }
        const size_t wo = (size_t)(j0 + rw) * NC + k0 + koff;
        const f4 w0 = *(const f4*)&Wp[wo], w1 = *(const f4*)&Wp[wo + 4];
        s8v bv;
#pragma unroll
        for (int i = 0; i < 4; i++) { bv[i] = bfbits(w0[i]); bv[4 + i] = bfbits(w1[i]); }
        __syncthreads();
        *(s8v*)&As[rw * 40 + koff] = av;
        *(s8v*)&Bs[rw * 40 + koff] = bv;
        __syncthreads();
        const s8v af = *(const s8v*)&As[(wv * 16 + l16) * 40 + quad * 8];
#pragma unroll
        for (int nt = 0; nt < 4; ++nt) {
            const s8v bf = *(const s8v*)&Bs[(nt * 16 + l16) * 40 + quad * 8];
            acc[nt] = __builtin_amdgcn_mfma_f32_16x16x32_bf16(af, bf, acc[nt], 0, 0, 0);
        }
    }
    __syncthreads();
#pragma unroll
    for (int nt = 0; nt < 4; ++nt)
#pragma unroll
        for (int r = 0; r < 4; ++r)
            Eb[(wv * 16 + quad * 4 + r) * 68 + nt * 16 + l16] = acc[nt][r];
    __syncthreads();
    const int cc = (t & 3) * 16;
#pragma unroll
    for (int i = 0; i < 4; ++i) {
        const f4 vo = *(const f4*)&Eb[rw * 68 + cc + 4 * i];
        *(f4*)&out[(size_t)o * BTC + (size_t)(n0 + rw) * NC + j0 + cc + 4 * i] = vo;
    }
}

extern "C" void kernel_launch(void* const* d_in, const int* in_sizes, int n_in,
                              void* d_out, int out_size, void* d_ws, size_t ws_size,
                              hipStream_t stream)
{
    const float* x  = (const float*)d_in[0];
    const float* xl = (const float*)d_in[1];
    const float* xu = (const float*)d_in[2];
    const float* Wa = (const float*)d_in[3];
    const float* Wp = (const float*)d_in[4];
    float* out = (float*)d_out;

    short* qkvb = (short*)d_ws;                       // 9*BHTD bf16  = 56.6 MB
    float* ybuf = (float*)(qkvb + (size_t)9 * BHTD);  // 1*BHTD f32   = 12.6 MB
    short* cand = (short*)(ybuf + (size_t)BHTD);      // 8*BHTD bf16  = 50.3 MB

    qkv_proj_mfma <<<dim3(36, 64),    256, 0, stream>>>(x, xl, xu, Wa, qkvb);
    flash_mfma_all<<<dim3(8, 24, 9),  256, 0, stream>>>(qkvb, ybuf, cand);
    out_proj_mfma <<<dim3(12, 64, 3), 256, 0, stream>>>(ybuf, cand, Wp, out);
}